// Round 7
// baseline (798.383 us; speedup 1.0000x reference)
//
#include <hip/hip_runtime.h>

#define D_MODEL 768
#define BN 16
#define NROWS 32768
#define SCALE 0.1f
#define LN_EPS 1e-5f
#define TPB 1024
#define WAVES 16
#define RPW 2                                 // rows per wave per pass
#define PASSES 4
#define ROWS_PER_BLOCK (WAVES * RPW * PASSES) // 128
#define NBLOCKS (NROWS / ROWS_PER_BLOCK)      // 256  -> exactly 1 block/CU

__device__ __forceinline__ void ld4(const float* p, float* d) {
    float4 v = *(const float4*)p;
    d[0] = v.x; d[1] = v.y; d[2] = v.z; d[3] = v.w;
}
// wave-uniform broadcast from a compile-time lane: v_readlane -> SGPR operand
__device__ __forceinline__ float bcast(float v, int l) {
    return __int_as_float(__builtin_amdgcn_readlane(__float_as_int(v), l));
}

// R6 post-mortem: spill volume tracked TOTAL rows/thread, not rows/pass ->
// the fully-unrolled PASSES loop let the scheduler interleave passes and
// multiply the live set. Fixes: (a) #pragma unroll 1 on the pass loop bounds
// the scheduling window to one pass (~55 live < 64); (b) xv's live range now
// ends at the down-proj -- the residual re-reads x (L2/L3-resident) in the
// up-proj epilogue.
__global__ __launch_bounds__(TPB)
void adapter_fused(const float* __restrict__ x,
                   const float* __restrict__ gamma,
                   const float* __restrict__ beta,
                   const float* __restrict__ w_down,
                   const float* __restrict__ b_down,
                   const float* __restrict__ w_up,
                   const float* __restrict__ b_up,
                   float* __restrict__ out)
{
    // LN folded into weights:  down_pre[k] = rs*(P[k] - mean*G[k]) + D[k] + bd[k]
    //   P[k] = sum_d x_d * (g_d * wd[d][k])   (s_wd holds g-prescaled wd^T)
    //   G[k] = sum_d g_d * wd[d][k],  D[k] = sum_d beta_d * wd[d][k]
    __shared__ __align__(16) float s_wd[BN * D_MODEL];  // 48 KB, [k][d], g-scaled
    __shared__ __align__(16) float s_wu[BN * D_MODEL];  // 48 KB, [k][d], SCALE-scaled
    __shared__ __align__(16) float s_bu[D_MODEL];       // SCALE * b_up
    __shared__ float s_g [D_MODEL];
    __shared__ float s_bt[D_MODEL];
    __shared__ float s_bd[BN];
    __shared__ float s_G [BN];
    __shared__ float s_D [BN];

    const int t    = threadIdx.x;
    const int w    = t >> 6;
    const int lane = t & 63;

    // ---------------- staging, once per block ----------------
    if (t < D_MODEL) {
        const float4* wr = (const float4*)(w_down + (size_t)t * BN);
        #pragma unroll
        for (int q = 0; q < 4; ++q) {
            float4 v = wr[q];
            s_wd[(q*4+0)*D_MODEL + t] = v.x;
            s_wd[(q*4+1)*D_MODEL + t] = v.y;
            s_wd[(q*4+2)*D_MODEL + t] = v.z;
            s_wd[(q*4+3)*D_MODEL + t] = v.w;
        }
        s_g [t] = gamma[t];
        s_bt[t] = beta[t];
        s_bu[t] = SCALE * b_up[t];
    }
    {   // w_up (16,768) straight copy, pre-scaled by SCALE
        const float4* src = (const float4*)w_up;
        float4* dst = (float4*)s_wu;
        #pragma unroll
        for (int q = 0; q < 3; ++q) {
            float4 v = src[t + q * TPB];
            v.x *= SCALE; v.y *= SCALE; v.z *= SCALE; v.w *= SCALE;
            dst[t + q * TPB] = v;
        }
    }
    if (t < BN) s_bd[t] = b_down[t];
    __syncthreads();

    // wave k (=w): compute G[k], D[k]; then scale s_wd row k by gamma
    {
        const int k = w;
        float Gp = 0.f, Dp = 0.f;
        #pragma unroll
        for (int q = 0; q < 3; ++q) {
            const int d0 = q * 256 + lane * 4;
            float wv[4], gv[4], bv[4];
            ld4(&s_wd[k * D_MODEL + d0], wv);
            ld4(&s_g [d0], gv);
            ld4(&s_bt[d0], bv);
            #pragma unroll
            for (int c = 0; c < 4; ++c) {
                Gp = fmaf(gv[c], wv[c], Gp);
                Dp = fmaf(bv[c], wv[c], Dp);
                wv[c] *= gv[c];
            }
            *(float4*)&s_wd[k * D_MODEL + d0] = make_float4(wv[0], wv[1], wv[2], wv[3]);
        }
        #pragma unroll
        for (int m = 32; m >= 1; m >>= 1) {
            Gp += __shfl_xor(Gp, m, 64);
            Dp += __shfl_xor(Dp, m, 64);
        }
        if (lane == 0) { s_G[k] = Gp; s_D[k] = Dp; }
    }
    __syncthreads();            // last block-wide barrier

    // block-invariant per-lane constants (k split: A = lane&7, B = 8+(lane&7))
    const int   kA  = lane & 7;
    const float GlA = s_G[kA],          GlB = s_G[8 + kA];
    const float DBA = s_D[kA] + s_bd[kA];
    const float DBB = s_D[8 + kA] + s_bd[8 + kA];
    const float inv_d = 1.0f / (float)D_MODEL;
    const int   dofs = lane * 4;        // chunked d-ownership: d = q*256 + lane*4

    #pragma unroll 1                    // CRITICAL: one pass in flight at a time
    for (int pp = 0; pp < PASSES; ++pp) {
        const int r0 = blockIdx.x * ROWS_PER_BLOCK + pp * (WAVES * RPW) + w * RPW;
        const float* xp = x + (size_t)r0 * D_MODEL;

        // ---- load 2 rows; each instr is contiguous 1KB/wave ----
        float xv[RPW][12];
        #pragma unroll
        for (int j = 0; j < RPW; ++j)
            #pragma unroll
            for (int q = 0; q < 3; ++q)
                ld4(xp + (size_t)j * D_MODEL + q * 256 + dofs, &xv[j][q * 4]);

        // ---- LN stats, independent in-wave butterflies ----
        float s1[RPW], s2[RPW];
        #pragma unroll
        for (int j = 0; j < RPW; ++j) {
            s1[j] = 0.f; s2[j] = 0.f;
            #pragma unroll
            for (int i = 0; i < 12; ++i) {
                s1[j] += xv[j][i];
                s2[j]  = fmaf(xv[j][i], xv[j][i], s2[j]);
            }
        }
        #pragma unroll
        for (int m = 32; m >= 1; m >>= 1) {
            #pragma unroll
            for (int j = 0; j < RPW; ++j) {
                s1[j] += __shfl_xor(s1[j], m, 64);
                s2[j] += __shfl_xor(s2[j], m, 64);
            }
        }
        float mean[RPW], rs[RPW];
        #pragma unroll
        for (int j = 0; j < RPW; ++j) {
            mean[j] = s1[j] * inv_d;
            rs[j]   = rsqrtf(fmaf(s2[j], inv_d, -(mean[j] * mean[j])) + LN_EPS);
        }

        // ---- down-proj on RAW x (LN folded), two 8-k batches ----
        float dnA[RPW], dnB[RPW];
        #pragma unroll
        for (int h = 0; h < 2; ++h) {          // h=0: k 0..7, h=1: k 8..15
            float p[RPW][8];
            #pragma unroll
            for (int j = 0; j < RPW; ++j)
                #pragma unroll
                for (int i = 0; i < 8; ++i) p[j][i] = 0.f;
            #pragma unroll
            for (int kk = 0; kk < 8; ++kk) {
                const int k = h * 8 + kk;
                #pragma unroll
                for (int q = 0; q < 3; ++q) {
                    float wv[4];
                    ld4(&s_wd[k * D_MODEL + q * 256 + dofs], wv);
                    #pragma unroll
                    for (int j = 0; j < RPW; ++j)
                        #pragma unroll
                        for (int c = 0; c < 4; ++c)
                            p[j][kk] = fmaf(xv[j][q * 4 + c], wv[c], p[j][kk]);
                }
            }
            // split-butterfly: 8 elems over 8-lane groups, then fold groups
            #pragma unroll
            for (int m = 4; m >= 1; m >>= 1) {
                const bool up = (lane & m) != 0;
                #pragma unroll
                for (int j = 0; j < RPW; ++j)
                    #pragma unroll
                    for (int i = 0; i < m; ++i) {
                        float s = up ? p[j][i] : p[j][i + m];
                        float r = __shfl_xor(s, m, 64);
                        p[j][i] = (up ? p[j][i + m] : p[j][i]) + r;
                    }
            }
            #pragma unroll
            for (int j = 0; j < RPW; ++j) {
                float v = p[j][0];
                v += __shfl_xor(v, 8, 64);
                v += __shfl_xor(v, 16, 64);
                v += __shfl_xor(v, 32, 64);
                // lane now holds P[k] for k = h*8 + (lane&7), summed over wave
                const float G  = h ? GlB : GlA;
                const float DB = h ? DBB : DBA;
                const float dv = fmaxf(fmaf(rs[j], fmaf(-mean[j], G, v), DB), 0.f);
                if (h) dnB[j] = dv; else dnA[j] = dv;
            }
        }
        // xv is DEAD here -- residual below re-reads x from L2/L3.

        // ---- up-proj + residual + store, per 256-d chunk (acc[2][4] live;
        // dn broadcast via v_readlane -> SGPR operand) ----
        float* op = out + (size_t)r0 * D_MODEL;
        #pragma unroll
        for (int q = 0; q < 3; ++q) {
            // issue residual reload early; hides under the 16-k FMA loop
            float rx[RPW][4];
            #pragma unroll
            for (int j = 0; j < RPW; ++j)
                ld4(xp + (size_t)j * D_MODEL + q * 256 + dofs, rx[j]);

            float buv[4];
            ld4(&s_bu[q * 256 + dofs], buv);
            float acc[RPW][4];
            #pragma unroll
            for (int j = 0; j < RPW; ++j)
                #pragma unroll
                for (int c = 0; c < 4; ++c) acc[j][c] = buv[c];

            #pragma unroll
            for (int k = 0; k < BN; ++k) {
                float wv[4];
                ld4(&s_wu[k * D_MODEL + q * 256 + dofs], wv);
                float dbk[RPW];
                #pragma unroll
                for (int j = 0; j < RPW; ++j)
                    dbk[j] = (k < 8) ? bcast(dnA[j], k) : bcast(dnB[j], k - 8);
                #pragma unroll
                for (int j = 0; j < RPW; ++j)
                    #pragma unroll
                    for (int c = 0; c < 4; ++c)
                        acc[j][c] = fmaf(dbk[j], wv[c], acc[j][c]);
            }
            #pragma unroll
            for (int j = 0; j < RPW; ++j) {
                float4 o;
                o.x = rx[j][0] + acc[j][0];
                o.y = rx[j][1] + acc[j][1];
                o.z = rx[j][2] + acc[j][2];
                o.w = rx[j][3] + acc[j][3];
                *(float4*)(op + (size_t)j * D_MODEL + q * 256 + dofs) = o;
            }
        }
    }
}

extern "C" void kernel_launch(void* const* d_in, const int* in_sizes, int n_in,
                              void* d_out, int out_size, void* d_ws, size_t ws_size,
                              hipStream_t stream) {
    const float* x       = (const float*)d_in[0];
    const float* gamma   = (const float*)d_in[1];
    const float* beta    = (const float*)d_in[2];
    const float* w_down  = (const float*)d_in[3];
    const float* b_down  = (const float*)d_in[4];
    const float* w_up    = (const float*)d_in[5];
    const float* b_up    = (const float*)d_in[6];
    float* out = (float*)d_out;

    adapter_fused<<<NBLOCKS, TPB, 0, stream>>>(x, gamma, beta, w_down, b_down,
                                               w_up, b_up, out);
}

// Round 8
// 204.955 us; speedup vs baseline: 3.8954x; 3.8954x over previous
//
#include <hip/hip_runtime.h>

#define D_MODEL 768
#define BN 16
#define NROWS 32768
#define SCALE 0.1f
#define LN_EPS 1e-5f
#define TPB 1024
#define WAVES 16
#define DPL 12                               // d's per lane (768/64)
#define PASSES 2
#define ROWS_PER_BLOCK (WAVES * 2 * PASSES)  // 64
#define NBLOCKS (NROWS / ROWS_PER_BLOCK)     // 512

// R7 post-mortem: R2 (78us, FETCH 56MB) was clean because butterfly outputs
// (non-rematerializable) lived ~2 instructions before going to LDS, while
// weights/x/dn flow through LDS (rematerializable under pressure). R3-R7
// kept butterfly results (dnA/dnB) in VGPRs across the whole up-proj ->
// scratch spills -> 1.3-1.5 GB HBM traffic. This kernel is R2 verbatim plus
// ONE delta: LN folded into staged weights via centering (x -= mean), which
// only removes work (48 ds_read + 48 FMA per pass) and shortens live ranges.

__device__ __forceinline__ void ld4(const float* p, float* d) {
    float4 v = *(const float4*)p;
    d[0] = v.x; d[1] = v.y; d[2] = v.z; d[3] = v.w;
}

__global__ __launch_bounds__(TPB)
void adapter_fused(const float* __restrict__ x,
                   const float* __restrict__ gamma,
                   const float* __restrict__ beta,
                   const float* __restrict__ w_down,
                   const float* __restrict__ b_down,
                   const float* __restrict__ w_up,
                   const float* __restrict__ b_up,
                   float* __restrict__ out)
{
    // down[k] = relu( rs * sum_d (x_d - mean) * (g_d*wd[d][k])  +  D[k] + bd[k] )
    //   where D[k] = sum_d beta_d * wd[d][k]   (LN affine folded at staging)
    __shared__ __align__(16) float s_wdT[BN * D_MODEL];   // [k][d], gamma-prescaled
    __shared__ __align__(16) float s_wu [BN * D_MODEL];   // [k][d], SCALE-prescaled
    __shared__ __align__(16) float s_g  [D_MODEL];
    __shared__ __align__(16) float s_bt [D_MODEL];
    __shared__ __align__(16) float s_buv[D_MODEL];        // SCALE * b_up
    __shared__ __align__(16) float s_bd [BN];
    __shared__ __align__(16) float s_D  [BN];
    __shared__ __align__(16) float s_dn [WAVES][2][BN];   // per-wave scratch

    const int t    = threadIdx.x;
    const int w    = t >> 6;
    const int lane = t & 63;

    // ---------------- one-time staging ----------------
    if (t < D_MODEL) {
        // transpose w_down (768,16) -> s_wdT[k][d]
        const float4* wr = (const float4*)(w_down + (size_t)t * BN);
        #pragma unroll
        for (int q = 0; q < 4; ++q) {
            float4 v = wr[q];
            s_wdT[(q*4+0)*D_MODEL + t] = v.x;
            s_wdT[(q*4+1)*D_MODEL + t] = v.y;
            s_wdT[(q*4+2)*D_MODEL + t] = v.z;
            s_wdT[(q*4+3)*D_MODEL + t] = v.w;
        }
        s_g  [t] = gamma[t];
        s_bt [t] = beta[t];
        s_buv[t] = SCALE * b_up[t];
    }
    {   // w_up (16,768) row-major straight copy, prescaled by SCALE
        const float4* src = (const float4*)w_up;
        float4* dst = (float4*)s_wu;
        #pragma unroll
        for (int q = 0; q < 3; ++q) {
            float4 v = src[t + q * TPB];
            v.x *= SCALE; v.y *= SCALE; v.z *= SCALE; v.w *= SCALE;
            dst[t + q * TPB] = v;
        }
    }
    if (t < BN) s_bd[t] = b_down[t];
    __syncthreads();

    // wave k(=w): D[k] = sum_d beta_d*wd[d][k]; then prescale row k by gamma
    {
        const int k = w;
        float Dp = 0.f;
        #pragma unroll
        for (int q = 0; q < 3; ++q) {
            const int d0 = q * 256 + lane * 4;
            float wv[4], gv[4], bv[4];
            ld4(&s_wdT[k * D_MODEL + d0], wv);
            ld4(&s_g [d0], gv);
            ld4(&s_bt[d0], bv);
            #pragma unroll
            for (int c = 0; c < 4; ++c) {
                Dp = fmaf(bv[c], wv[c], Dp);
                wv[c] *= gv[c];
            }
            *(float4*)&s_wdT[k * D_MODEL + d0] = make_float4(wv[0], wv[1], wv[2], wv[3]);
        }
        #pragma unroll
        for (int m = 32; m >= 1; m >>= 1)
            Dp += __shfl_xor(Dp, m, 64);
        if (lane == 0) s_D[k] = Dp;
    }
    __syncthreads();            // last block-wide barrier

    const int   base = lane * DPL;        // this lane's d-range [base, base+12)
    const float* wdp = s_wdT + base;
    const float* wup = s_wu  + base;
    const float DBl  = s_D[lane & 15] + s_bd[lane & 15];
    const float inv_d = 1.0f / (float)D_MODEL;

    for (int pp = 0; pp < PASSES; ++pp) {
        const int r0 = blockIdx.x * ROWS_PER_BLOCK + pp * (WAVES * 2) + w * 2;
        const float* xp0 = x + (size_t)r0 * D_MODEL + base;
        const float* xp1 = xp0 + D_MODEL;

        // ---- load 2 rows (48 B/lane contiguous) ----
        float xa[DPL], xb[DPL];
        ld4(xp0 + 0, xa + 0); ld4(xp0 + 4, xa + 4); ld4(xp0 + 8, xa + 8);
        ld4(xp1 + 0, xb + 0); ld4(xp1 + 4, xb + 4); ld4(xp1 + 8, xb + 8);

        // ---- LN stats, fully in-wave ----
        float s1a = 0.f, s2a = 0.f, s1b = 0.f, s2b = 0.f;
        #pragma unroll
        for (int i = 0; i < DPL; ++i) {
            s1a += xa[i]; s2a = fmaf(xa[i], xa[i], s2a);
            s1b += xb[i]; s2b = fmaf(xb[i], xb[i], s2b);
        }
        #pragma unroll
        for (int m = 32; m >= 1; m >>= 1) {
            s1a += __shfl_xor(s1a, m, 64); s2a += __shfl_xor(s2a, m, 64);
            s1b += __shfl_xor(s1b, m, 64); s2b += __shfl_xor(s2b, m, 64);
        }
        const float ma  = s1a * inv_d;
        const float rsa = rsqrtf(fmaf(s2a, inv_d, -(ma * ma)) + LN_EPS);
        const float mb  = s1b * inv_d;
        const float rsb = rsqrtf(fmaf(s2b, inv_d, -(mb * mb)) + LN_EPS);

        // ---- center x in place (replaces the whole normalize pass) ----
        #pragma unroll
        for (int i = 0; i < DPL; ++i) { xa[i] -= ma; xb[i] -= mb; }

        // ---- down-proj: gamma-prescaled weights from LDS, both rows ----
        float p0[BN], p1[BN];
        #pragma unroll
        for (int k = 0; k < BN; ++k) { p0[k] = 0.f; p1[k] = 0.f; }
        #pragma unroll
        for (int k = 0; k < BN; ++k) {
            float wv[DPL];
            ld4(wdp + k * D_MODEL + 0, wv + 0);
            ld4(wdp + k * D_MODEL + 4, wv + 4);
            ld4(wdp + k * D_MODEL + 8, wv + 8);
            #pragma unroll
            for (int i = 0; i < DPL; ++i) {
                p0[k] = fmaf(xa[i], wv[i], p0[k]);
                p1[k] = fmaf(xb[i], wv[i], p1[k]);
            }
        }

        // ---- in-wave split-butterfly reduce of p[16] ----
        #pragma unroll
        for (int m = 8; m >= 1; m >>= 1) {
            const bool up = (lane & m) != 0;
            #pragma unroll
            for (int i = 0; i < m; ++i) {
                float sa = up ? p0[i] : p0[i + m];
                float sb = up ? p1[i] : p1[i + m];
                float ra = __shfl_xor(sa, m, 64);
                float rb = __shfl_xor(sb, m, 64);
                p0[i] = (up ? p0[i + m] : p0[i]) + ra;
                p1[i] = (up ? p1[i + m] : p1[i]) + rb;
            }
        }
        float va = p0[0];
        va += __shfl_xor(va, 16, 64); va += __shfl_xor(va, 32, 64);
        float vb = p1[0];
        vb += __shfl_xor(vb, 16, 64); vb += __shfl_xor(vb, 32, 64);

        // ---- rs/D/bias/ReLU, stash in per-wave LDS (no block barrier);
        // butterfly outputs die IMMEDIATELY (the R2 property that avoids spill)
        if (lane < BN) {
            s_dn[w][0][lane] = fmaxf(fmaf(rsa, va, DBl), 0.f);
            s_dn[w][1][lane] = fmaxf(fmaf(rsb, vb, DBl), 0.f);
        }

        // issue residual x reload early (L2/L3-warm); hides under up-proj
        float ra0[DPL], ra1[DPL];
        ld4(xp0 + 0, ra0 + 0); ld4(xp0 + 4, ra0 + 4); ld4(xp0 + 8, ra0 + 8);
        ld4(xp1 + 0, ra1 + 0); ld4(xp1 + 4, ra1 + 4); ld4(xp1 + 8, ra1 + 8);

        // same-wave DS ordering + keep compiler from hoisting the reads
        asm volatile("s_waitcnt lgkmcnt(0)" ::: "memory");
        __builtin_amdgcn_sched_barrier(0);

        float dn0[BN], dn1[BN];
        ld4(&s_dn[w][0][0], dn0 + 0);  ld4(&s_dn[w][0][4], dn0 + 4);
        ld4(&s_dn[w][0][8], dn0 + 8);  ld4(&s_dn[w][0][12], dn0 + 12);
        ld4(&s_dn[w][1][0], dn1 + 0);  ld4(&s_dn[w][1][4], dn1 + 4);
        ld4(&s_dn[w][1][8], dn1 + 8);  ld4(&s_dn[w][1][12], dn1 + 12);

        // ---- up-proj: acc starts at SCALE*b_up; SCALE-prescaled weights ----
        float a0[DPL], a1[DPL];
        {
            float bu_[DPL];
            ld4(s_buv + base + 0, bu_ + 0);
            ld4(s_buv + base + 4, bu_ + 4);
            ld4(s_buv + base + 8, bu_ + 8);
            #pragma unroll
            for (int i = 0; i < DPL; ++i) { a0[i] = bu_[i]; a1[i] = bu_[i]; }
        }
        #pragma unroll
        for (int k = 0; k < BN; ++k) {
            float wv[DPL];
            ld4(wup + k * D_MODEL + 0, wv + 0);
            ld4(wup + k * D_MODEL + 4, wv + 4);
            ld4(wup + k * D_MODEL + 8, wv + 8);
            #pragma unroll
            for (int i = 0; i < DPL; ++i) {
                a0[i] = fmaf(dn0[k], wv[i], a0[i]);
                a1[i] = fmaf(dn1[k], wv[i], a1[i]);
            }
        }

        // ---- residual add + coalesced float4 stores ----
        float* op0 = out + (size_t)r0 * D_MODEL + base;
        float* op1 = op0 + D_MODEL;
        #pragma unroll
        for (int q = 0; q < 3; ++q) {
            float4 o0, o1;
            o0.x = ra0[q*4+0] + a0[q*4+0];
            o0.y = ra0[q*4+1] + a0[q*4+1];
            o0.z = ra0[q*4+2] + a0[q*4+2];
            o0.w = ra0[q*4+3] + a0[q*4+3];
            o1.x = ra1[q*4+0] + a1[q*4+0];
            o1.y = ra1[q*4+1] + a1[q*4+1];
            o1.z = ra1[q*4+2] + a1[q*4+2];
            o1.w = ra1[q*4+3] + a1[q*4+3];
            ((float4*)op0)[q] = o0;
            ((float4*)op1)[q] = o1;
        }
    }
}

extern "C" void kernel_launch(void* const* d_in, const int* in_sizes, int n_in,
                              void* d_out, int out_size, void* d_ws, size_t ws_size,
                              hipStream_t stream) {
    const float* x       = (const float*)d_in[0];
    const float* gamma   = (const float*)d_in[1];
    const float* beta    = (const float*)d_in[2];
    const float* w_down  = (const float*)d_in[3];
    const float* b_down  = (const float*)d_in[4];
    const float* w_up    = (const float*)d_in[5];
    const float* b_up    = (const float*)d_in[6];
    float* out = (float*)d_out;

    adapter_fused<<<NBLOCKS, TPB, 0, stream>>>(x, gamma, beta, w_down, b_down,
                                               w_up, b_up, out);
}